// Round 9
// baseline (430.013 us; speedup 1.0000x reference)
//
#include <hip/hip_runtime.h>
#include <hip/hip_cooperative_groups.h>
#include <math.h>

namespace cg = cooperative_groups;

#define NCELLS 2097152  // 128^3
#define CAP 32          // bucket capacity (mean occupancy 8; P(>32) ~ 1e-10)

// ================= complex helpers =================
__device__ __forceinline__ float2 cadd(float2 a, float2 b){ return make_float2(a.x+b.x, a.y+b.y); }
__device__ __forceinline__ float2 csub(float2 a, float2 b){ return make_float2(a.x-b.x, a.y-b.y); }
template<int DIR>
__device__ __forceinline__ float2 ctw(float2 b, float2 w) {
  if (DIR < 0) return make_float2(b.x*w.x - b.y*w.y, b.x*w.y + b.y*w.x);
  else         return make_float2(b.x*w.x + b.y*w.y, b.y*w.x - b.x*w.y);
}

// tw[Ns+k] = exp(-i*pi*k/Ns), indices 1..127
__device__ __forceinline__ void init_tw(float2* tw, int tid) {
  if (tid >= 1 && tid < 128) {
    int Ns = 1 << (31 - __clz(tid));
    int k = tid - Ns;
    float ang = -3.14159265358979323846f * (float)k / (float)Ns;
    float s, c;
    sincosf(ang, &s, &c);
    tw[tid] = make_float2(c, s);
  }
}

// ===== mixed-radix Stockham FFT of 16 lines of 128, in-place at (base, line-stride ls,
// elem-stride es), scratch S[16][128], 512 threads, radix 4/4/4/2, natural->natural order.
template<int DIR>
__device__ __forceinline__ void fft16(float2* __restrict__ base, int ls, int es,
                                      float2 (*__restrict__ S)[128],
                                      const float2* __restrict__ tw, int tid) {
  int l = tid >> 5, j = tid & 31;
  float2* B = base + l * ls;
  { // stage 0: radix-4, Ns=1, B -> S
    float2 a = B[j*es], b = B[(j+32)*es], c = B[(j+64)*es], d = B[(j+96)*es];
    float2 t0 = cadd(a,c), t1 = csub(a,c), t2 = cadd(b,d), t3s = csub(b,d);
    float2 t3 = (DIR<0) ? make_float2(t3s.y,-t3s.x) : make_float2(-t3s.y,t3s.x);
    int o = j << 2;
    S[l][o] = cadd(t0,t2); S[l][o+1] = cadd(t1,t3);
    S[l][o+2] = csub(t0,t2); S[l][o+3] = csub(t1,t3);
  }
  __syncthreads();
  { // stage 1: radix-4, Ns=4, S -> B
    int k = j & 3;
    float2 a = S[l][j], b = S[l][j+32], c = S[l][j+64], d = S[l][j+96];
    float2 w1 = tw[8+k], w2 = tw[4+k];
    float2 w3 = make_float2(w1.x*w2.x - w1.y*w2.y, w1.x*w2.y + w1.y*w2.x);
    b = ctw<DIR>(b,w1); c = ctw<DIR>(c,w2); d = ctw<DIR>(d,w3);
    float2 t0 = cadd(a,c), t1 = csub(a,c), t2 = cadd(b,d), t3s = csub(b,d);
    float2 t3 = (DIR<0) ? make_float2(t3s.y,-t3s.x) : make_float2(-t3s.y,t3s.x);
    int o = ((j>>2)<<4) + k;
    B[o*es] = cadd(t0,t2); B[(o+4)*es] = cadd(t1,t3);
    B[(o+8)*es] = csub(t0,t2); B[(o+12)*es] = csub(t1,t3);
  }
  __syncthreads();
  { // stage 2: radix-4, Ns=16, B -> S
    int k = j & 15;
    float2 a = B[j*es], b = B[(j+32)*es], c = B[(j+64)*es], d = B[(j+96)*es];
    float2 w1 = tw[32+k], w2 = tw[16+k];
    float2 w3 = make_float2(w1.x*w2.x - w1.y*w2.y, w1.x*w2.y + w1.y*w2.x);
    b = ctw<DIR>(b,w1); c = ctw<DIR>(c,w2); d = ctw<DIR>(d,w3);
    float2 t0 = cadd(a,c), t1 = csub(a,c), t2 = cadd(b,d), t3s = csub(b,d);
    float2 t3 = (DIR<0) ? make_float2(t3s.y,-t3s.x) : make_float2(-t3s.y,t3s.x);
    int o = ((j>>4)<<6) + k;
    S[l][o] = cadd(t0,t2); S[l][o+16] = cadd(t1,t3);
    S[l][o+32] = csub(t0,t2); S[l][o+48] = csub(t1,t3);
  }
  __syncthreads();
  // stage 3: radix-2, Ns=64, S -> B
  #pragma unroll
  for (int q = 0; q < 2; q++) {
    int t = tid + q*512;
    int l2 = t >> 6, j2 = t & 63;
    float2 a = S[l2][j2], b = S[l2][j2+64];
    b = ctw<DIR>(b, tw[64+j2]);
    float2* D = base + l2*ls;
    D[j2*es] = cadd(a,b); D[(j2+64)*es] = csub(a,b);
  }
  __syncthreads();
}

// ================= shared-memory union across phases =================
union SharedU {
  struct { float2 sp[16][129]; float2 s2[16][129]; float2 S[16][128]; } zr;            // 49 KB
  struct { float2 T0[16][129]; float2 T1[16][129]; float2 T2[16][129]; float2 S[16][128]; } xs; // 66 KB
  struct { float2 sc[16][129]; float2 S[16][128]; } ln;                                 // 33 KB
};

// ================= the whole pipeline as one cooperative kernel =================
__global__ __launch_bounds__(512, 4)
void mega(const float* __restrict__ pts, const float* __restrict__ nrm,
          int* __restrict__ counts, float4* __restrict__ bkt,
          float2* __restrict__ V0, float2* __restrict__ V1, float2* __restrict__ V2,
          float* __restrict__ chi, float* __restrict__ sum,
          float* __restrict__ out, int npts) {
  cg::grid_group grid = cg::this_grid();
  __shared__ SharedU u;
  __shared__ float2 tw[128];
  const int tid = threadIdx.x, bid = blockIdx.x;
  const int NB = gridDim.x;
  const int nthreads = NB * 512;
  const int gid = bid * 512 + tid;

  init_tw(tw, tid);

  // ---- phase 0: zero counts + sum ----
  for (int i = gid; i < 16384; i += nthreads) counts[i] = 0;
  if (gid == 0) sum[0] = 0.0f;
  grid.sync();

  // ---- phase 1: direct bucket scatter ----
  for (int i = gid; i < npts; i += nthreads) {
    float px = pts[3*i+0], py = pts[3*i+1], pz = pts[3*i+2];
    int lx = ((int)floorf(px * 128.0f)) & 127;
    int ly = ((int)floorf(py * 128.0f)) & 127;
    int b = (lx << 7) + ly;
    int slot = atomicAdd(counts + b, 1);
    if (slot < CAP) {
      bkt[(size_t)(b * CAP + slot) * 2]     = make_float4(px, py, pz, 0.0f);
      bkt[(size_t)(b * CAP + slot) * 2 + 1] = make_float4(nrm[3*i+0], nrm[3*i+1], nrm[3*i+2], 0.0f);
    }
  }
  grid.sync();

  // ---- phase 2: fused raster + z-FFT + Hermitian z-unpack -> V0,V1,V2 [w][x][y] ----
  for (int t = bid; t < 1024; t += NB) {
    __syncthreads();
    int x = t >> 3, y0 = (t & 7) << 4;
    for (int e = tid; e < 16 * 129; e += 512) {
      (&u.zr.sp[0][0])[e] = make_float2(0.0f, 0.0f);
      (&u.zr.s2[0][0])[e] = make_float2(0.0f, 0.0f);
    }
    __syncthreads();
    for (int tt = tid; tt < 2 * 17 * CAP; tt += 512) {
      int side = tt / (17 * CAP);
      int jj = tt - side * (17 * CAP);
      int j = jj >> 5, slot = jj & 31;          // CAP == 32
      int by = (y0 - 1 + j) & 127;
      int bx = side ? ((x + 127) & 127) : x;
      int b = (bx << 7) + by;
      int cnt = counts[b]; if (cnt > CAP) cnt = CAP;
      if (slot < cnt) {
        float4 P  = bkt[(size_t)(b * CAP + slot) * 2];
        float4 Nm = bkt[(size_t)(b * CAP + slot) * 2 + 1];
        float tx = P.x*128.0f, ty = P.y*128.0f, tz = P.z*128.0f;
        float fx = tx - floorf(tx), fy = ty - floorf(ty), fz = tz - floorf(tz);
        int ly = ((int)floorf(ty)) & 127, lz = ((int)floorf(tz)) & 127;
        int z1 = (lz + 1) & 127;
        float wx = side ? fx : (1.0f - fx);
        #pragma unroll
        for (int yc = 0; yc < 2; yc++) {
          int yy = yc ? ((ly + 1) & 127) : ly;
          float wy = yc ? fy : (1.0f - fy);
          int l = (yy - y0) & 127;
          if (l < 16) {
            float w0 = wx*wy*(1.0f - fz), w1 = wx*wy*fz;
            atomicAdd(&u.zr.sp[l][lz].x, w0*Nm.x); atomicAdd(&u.zr.sp[l][lz].y, w0*Nm.y);
            atomicAdd(&u.zr.sp[l][z1].x, w1*Nm.x); atomicAdd(&u.zr.sp[l][z1].y, w1*Nm.y);
            atomicAdd(&u.zr.s2[l][lz].x, w0*Nm.z);
            atomicAdd(&u.zr.s2[l][z1].x, w1*Nm.z);
          }
        }
      }
    }
    __syncthreads();
    fft16<-1>(&u.zr.sp[0][0], 129, 1, u.zr.S, tw, tid);
    for (int e = tid; e < 65 * 16; e += 512) {
      int w = e >> 4, l = e & 15;
      float2 A = u.zr.sp[l][w];
      float2 B = u.zr.sp[l][(128 - w) & 127];
      size_t o = (size_t)w * 16384 + x * 128 + y0 + l;
      V0[o] = make_float2(0.5f * (A.x + B.x), 0.5f * (A.y - B.y));
      V1[o] = make_float2(0.5f * (A.y + B.y), 0.5f * (B.x - A.x));
    }
    fft16<-1>(&u.zr.s2[0][0], 129, 1, u.zr.S, tw, tid);
    for (int e = tid; e < 65 * 16; e += 512) {
      int w = e >> 4, l = e & 15;
      V2[(size_t)w * 16384 + x * 128 + y0 + l] = u.zr.s2[l][w];
    }
  }
  grid.sync();

  // ---- phase 3: forward y-FFT, in place, 3 channels x 520 tiles ----
  for (int t = bid; t < 1560; t += NB) {
    __syncthreads();
    int idx = t; float2* base = V0;
    if (t >= 1040)      { base = V2; idx = t - 1040; }
    else if (t >= 520)  { base = V1; idx = t - 520; }
    float2* D = base + (size_t)idx * 2048;
    for (int e = tid; e < 2048; e += 512) u.ln.sc[e >> 7][e & 127] = D[e];
    __syncthreads();
    fft16<-1>(&u.ln.sc[0][0], 129, 1, u.ln.S, tw, tid);
    for (int e = tid; e < 2048; e += 512) D[e] = u.ln.sc[e >> 7][e & 127];
  }
  grid.sync();

  // ---- phase 4: fwd x-FFT (3ch) + spectral + inv x-FFT, in place into V0 ----
  for (int t = bid; t < 520; t += NB) {
    __syncthreads();
    int w = t >> 3, ky0 = (t & 7) << 4;
    for (int e = tid; e < 2048; e += 512) {
      int xx = e >> 4, i = e & 15;
      size_t o = (size_t)w * 16384 + xx * 128 + ky0 + i;
      u.xs.T0[i][xx] = V0[o];
      u.xs.T1[i][xx] = V1[o];
      u.xs.T2[i][xx] = V2[o];
    }
    __syncthreads();
    fft16<-1>(&u.xs.T0[0][0], 129, 1, u.xs.S, tw, tid);
    fft16<-1>(&u.xs.T1[0][0], 129, 1, u.xs.S, tw, tid);
    fft16<-1>(&u.xs.T2[0][0], 129, 1, u.xs.S, tw, tid);
    float fz = (float)(w < 64 ? w : w - 128);
    for (int e = tid; e < 2048; e += 512) {
      int i = e >> 7, kx = e & 127;
      int ky = ky0 + i;
      float2 v0 = u.xs.T0[i][kx], v1 = u.xs.T1[i][kx], v2 = u.xs.T2[i][kx];
      float fx = (float)(kx < 64 ? kx : kx - 128);
      float fy = (float)(ky < 64 ? ky : ky - 128);
      float u2 = fx * fx + fy * fy + fz * fz;
      float gg = __expf(-0.0030517578125f * u2);   // -2*(5/128)^2*u2
      float coef = gg / (6.28318530717958648f * (u2 + 1e-6f)) * (1.0f / 2097152.0f);
      float dre = fx * v0.x + fy * v1.x + fz * v2.x;
      float dim = fx * v0.y + fy * v1.y + fz * v2.y;
      u.xs.T0[i][kx] = make_float2(coef * dim, -coef * dre);  // (-i)*(a+bi) = (b,-a)
    }
    __syncthreads();
    fft16<1>(&u.xs.T0[0][0], 129, 1, u.xs.S, tw, tid);
    for (int e = tid; e < 2048; e += 512) {
      int xx = e >> 4, i = e & 15;
      V0[(size_t)w * 16384 + xx * 128 + ky0 + i] = u.xs.T0[i][xx];
    }
  }
  grid.sync();

  // ---- phase 5: inverse y-FFT, in place (V0), 520 tiles ----
  for (int t = bid; t < 520; t += NB) {
    __syncthreads();
    float2* D = V0 + (size_t)t * 2048;
    for (int e = tid; e < 2048; e += 512) u.ln.sc[e >> 7][e & 127] = D[e];
    __syncthreads();
    fft16<1>(&u.ln.sc[0][0], 129, 1, u.ln.S, tw, tid);
    for (int e = tid; e < 2048; e += 512) D[e] = u.ln.sc[e >> 7][e & 127];
  }
  grid.sync();

  // ---- phase 6: Hermitian c2r inverse w-FFT -> chi [x][y][z] ----
  for (int t = bid; t < 1024; t += NB) {
    __syncthreads();
    int x = t >> 3, y0 = (t & 7) << 4;
    for (int e = tid; e < 65 * 16; e += 512) {
      int w = e >> 4, i = e & 15;
      u.ln.sc[i][w] = V0[(size_t)w * 16384 + x * 128 + y0 + i];
    }
    __syncthreads();
    for (int e = tid; e < 63 * 16; e += 512) {
      int w = 65 + (e >> 4), i = e & 15;
      float2 c = u.ln.sc[i][128 - w];
      u.ln.sc[i][w] = make_float2(c.x, -c.y);
    }
    __syncthreads();
    fft16<1>(&u.ln.sc[0][0], 129, 1, u.ln.S, tw, tid);
    for (int e = tid; e < 2048; e += 512) {
      int i = e >> 7, z = e & 127;
      chi[(x * 128 + y0 + i) * 128 + z] = u.ln.sc[i][z].x;
    }
  }
  grid.sync();

  // ---- phase 7: trilinear interpolation + mean accumulation ----
  {
    float v = 0.0f;
    for (int i = gid; i < npts; i += nthreads) {
      float tx = pts[3*i+0] * 128.0f, ty = pts[3*i+1] * 128.0f, tz = pts[3*i+2] * 128.0f;
      int lx = (int)floorf(tx), ly = (int)floorf(ty), lz = (int)floorf(tz);
      float fx = tx - (float)lx, fy = ty - (float)ly, fz = tz - (float)lz;
      lx &= 127; ly &= 127; lz &= 127;
      int hx = (lx + 1) & 127, hy = (ly + 1) & 127, hz = (lz + 1) & 127;
      #pragma unroll
      for (int c = 0; c < 8; c++) {
        int ix = (c & 4) ? hx : lx; float wx = (c & 4) ? fx : 1.0f - fx;
        int iy = (c & 2) ? hy : ly; float wy = (c & 2) ? fy : 1.0f - fy;
        int iz = (c & 1) ? hz : lz; float wz = (c & 1) ? fz : 1.0f - fz;
        v += wx * wy * wz * chi[(ix << 14) + (iy << 7) + iz];
      }
    }
    #pragma unroll
    for (int off = 32; off > 0; off >>= 1) v += __shfl_down(v, off, 64);
    if ((tid & 63) == 0) atomicAdd(sum, v);
  }
  grid.sync();

  // ---- phase 8: finalize ----
  {
    float mean = sum[0] / (float)npts;
    float scale = 0.5f / fabsf(chi[0] - mean);
    for (int i = gid; i < NCELLS; i += nthreads) out[i] = scale * (chi[i] - mean);
  }
}

// ================= launch =================
extern "C" void kernel_launch(void* const* d_in, const int* in_sizes, int n_in,
                              void* d_out, int out_size, void* d_ws, size_t ws_size,
                              hipStream_t stream) {
  const float* pts = (const float*)d_in[0];
  const float* nrm = (const float*)d_in[1];
  float* out = (float*)d_out;
  int npts = in_sizes[0] / 3;  // 131072

  const size_t HSLICES = 65ull * 16384;  // half-spectrum elems per channel
  char* p = (char*)d_ws;
  float2* V0     = (float2*)p;  p += HSLICES * sizeof(float2);                 // 8.5 MB
  float2* V1     = (float2*)p;  p += HSLICES * sizeof(float2);                 // 8.5 MB
  float2* V2     = (float2*)p;  p += HSLICES * sizeof(float2);                 // 8.5 MB
  float4* bkt    = (float4*)p;  p += (size_t)16384 * CAP * 2 * sizeof(float4); // 16.8 MB
  float*  chi    = (float*)p;   p += (size_t)NCELLS * sizeof(float);           // 8.4 MB
  int*    counts = (int*)p;     p += 16384 * sizeof(int);
  float*  sum    = (float*)p;

  // co-residency-safe grid size (phases are grid-stride, any NB works)
  int blocksPerCU = 0;
  hipError_t e = hipOccupancyMaxActiveBlocksPerMultiprocessor(&blocksPerCU, (const void*)mega, 512, 0);
  int nb = (e == hipSuccess && blocksPerCU > 0) ? blocksPerCU * 256 : 256;
  if (nb > 512) nb = 512;

  void* args[] = { (void*)&pts, (void*)&nrm, (void*)&counts, (void*)&bkt,
                   (void*)&V0, (void*)&V1, (void*)&V2, (void*)&chi,
                   (void*)&sum, (void*)&out, (void*)&npts };
  hipLaunchCooperativeKernel((const void*)mega, dim3(nb), dim3(512), args, 0, stream);
}

// Round 10
// 257.298 us; speedup vs baseline: 1.6713x; 1.6713x over previous
//
#include <hip/hip_runtime.h>
#include <math.h>

#define NCELLS 2097152  // 128^3
#define CAP 32          // bucket capacity (mean occupancy 8; P(>32) ~ 1e-10)

// ================= complex helpers =================
__device__ __forceinline__ float2 cadd(float2 a, float2 b){ return make_float2(a.x+b.x, a.y+b.y); }
__device__ __forceinline__ float2 csub(float2 a, float2 b){ return make_float2(a.x-b.x, a.y-b.y); }
template<int DIR>
__device__ __forceinline__ float2 ctw(float2 b, float2 w) {
  if (DIR < 0) return make_float2(b.x*w.x - b.y*w.y, b.x*w.y + b.y*w.x);
  else         return make_float2(b.x*w.x + b.y*w.y, b.y*w.x - b.x*w.y);
}

// tw[Ns+k] = exp(-i*pi*k/Ns), indices 1..127
__device__ __forceinline__ void init_tw(float2* tw, int tid) {
  if (tid >= 1 && tid < 128) {
    int Ns = 1 << (31 - __clz(tid));
    int k = tid - Ns;
    float ang = -3.14159265358979323846f * (float)k / (float)Ns;
    float s, c;
    sincosf(ang, &s, &c);
    tw[tid] = make_float2(c, s);
  }
}

// ===== Stockham FFT, 16 lines of 128 in LDS, radix 4-4-8 (3 stages, last in-place).
// base rows stride ls (=129 padded). Scratch S[16][128]. 512 threads.
template<int DIR>
__device__ __forceinline__ void fft16(float2* __restrict__ base, int ls,
                                      float2 (*__restrict__ S)[128],
                                      const float2* __restrict__ tw, int tid) {
  const float SQ2 = 0.70710678118654752f;
  int l = tid >> 5, j = tid & 31;
  float2* B = base + l * ls;
  { // stage 0: radix-4, Ns=1, B -> S
    float2 a = B[j], b = B[j+32], c = B[j+64], d = B[j+96];
    float2 t0 = cadd(a,c), t1 = csub(a,c), t2 = cadd(b,d), t3s = csub(b,d);
    float2 t3 = (DIR<0) ? make_float2(t3s.y,-t3s.x) : make_float2(-t3s.y,t3s.x);
    int o = j << 2;
    S[l][o] = cadd(t0,t2); S[l][o+1] = cadd(t1,t3);
    S[l][o+2] = csub(t0,t2); S[l][o+3] = csub(t1,t3);
  }
  __syncthreads();
  { // stage 1: radix-4, Ns=4, S -> B
    int k = j & 3;
    float2 a = S[l][j], b = S[l][j+32], c = S[l][j+64], d = S[l][j+96];
    float2 w1 = tw[8+k], w2 = tw[4+k];
    float2 w3 = make_float2(w1.x*w2.x - w1.y*w2.y, w1.x*w2.y + w1.y*w2.x);
    b = ctw<DIR>(b,w1); c = ctw<DIR>(c,w2); d = ctw<DIR>(d,w3);
    float2 t0 = cadd(a,c), t1 = csub(a,c), t2 = cadd(b,d), t3s = csub(b,d);
    float2 t3 = (DIR<0) ? make_float2(t3s.y,-t3s.x) : make_float2(-t3s.y,t3s.x);
    int o = ((j>>2)<<4) + k;
    B[o] = cadd(t0,t2); B[o+4] = cadd(t1,t3);
    B[o+8] = csub(t0,t2); B[o+12] = csub(t1,t3);
  }
  __syncthreads();
  if (tid < 256) { // stage 2: radix-8, Ns=16, B -> B IN PLACE (task j owns {k+16m})
    int l2 = tid >> 4, k = tid & 15;
    float2* B2 = base + l2 * ls;
    float2 x0=B2[k],    x1=B2[k+16], x2=B2[k+32], x3=B2[k+48],
           x4=B2[k+64], x5=B2[k+80], x6=B2[k+96], x7=B2[k+112];
    float2 w1 = tw[64+k], w2 = tw[32+k], w4 = tw[16+k];
    float2 w3 = make_float2(w1.x*w2.x - w1.y*w2.y, w1.x*w2.y + w1.y*w2.x);
    float2 w5 = make_float2(w4.x*w1.x - w4.y*w1.y, w4.x*w1.y + w4.y*w1.x);
    float2 w6 = make_float2(w4.x*w2.x - w4.y*w2.y, w4.x*w2.y + w4.y*w2.x);
    float2 w7 = make_float2(w4.x*w3.x - w4.y*w3.y, w4.x*w3.y + w4.y*w3.x);
    x1 = ctw<DIR>(x1,w1); x2 = ctw<DIR>(x2,w2); x3 = ctw<DIR>(x3,w3);
    x4 = ctw<DIR>(x4,w4); x5 = ctw<DIR>(x5,w5); x6 = ctw<DIR>(x6,w6); x7 = ctw<DIR>(x7,w7);
    float2 e0=cadd(x0,x4), e1=cadd(x1,x5), e2=cadd(x2,x6), e3=cadd(x3,x7);
    float2 o0=csub(x0,x4), o1=csub(x1,x5), o2=csub(x2,x6), o3=csub(x3,x7);
    // odd part * W8^n (conjugated for inverse)
    o1 = (DIR<0)? make_float2(SQ2*(o1.x+o1.y), SQ2*(o1.y-o1.x))
                : make_float2(SQ2*(o1.x-o1.y), SQ2*(o1.x+o1.y));
    o2 = (DIR<0)? make_float2(o2.y,-o2.x) : make_float2(-o2.y,o2.x);
    o3 = (DIR<0)? make_float2(SQ2*(o3.y-o3.x), -SQ2*(o3.x+o3.y))
                : make_float2(-SQ2*(o3.x+o3.y), SQ2*(o3.x-o3.y));
    { // DFT4(evens) -> X[2r] at k+32r
      float2 t0=cadd(e0,e2), t1=csub(e0,e2), t2=cadd(e1,e3), t3s=csub(e1,e3);
      float2 t3 = (DIR<0)? make_float2(t3s.y,-t3s.x) : make_float2(-t3s.y,t3s.x);
      B2[k]    = cadd(t0,t2); B2[k+32] = cadd(t1,t3);
      B2[k+64] = csub(t0,t2); B2[k+96] = csub(t1,t3);
    }
    { // DFT4(odds) -> X[2r+1] at k+16+32r
      float2 t0=cadd(o0,o2), t1=csub(o0,o2), t2=cadd(o1,o3), t3s=csub(o1,o3);
      float2 t3 = (DIR<0)? make_float2(t3s.y,-t3s.x) : make_float2(-t3s.y,t3s.x);
      B2[k+16] = cadd(t0,t2); B2[k+48] = cadd(t1,t3);
      B2[k+80] = csub(t0,t2); B2[k+112] = csub(t1,t3);
    }
  }
  __syncthreads();
}

// ================= direct bucket scatter (fixed capacity, no scan) =================
__global__ __launch_bounds__(256) void scatter_direct(const float* __restrict__ pts,
                                                      const float* __restrict__ nrm,
                                                      int* __restrict__ counts,
                                                      float4* __restrict__ bkt, int npts) {
  int i = blockIdx.x * 256 + threadIdx.x;
  if (i >= npts) return;
  float px = pts[3*i+0], py = pts[3*i+1], pz = pts[3*i+2];
  int lx = ((int)floorf(px * 128.0f)) & 127;
  int ly = ((int)floorf(py * 128.0f)) & 127;
  int b = (lx << 7) + ly;
  int slot = atomicAdd(counts + b, 1);
  if (slot < CAP) {
    bkt[(size_t)(b * CAP + slot) * 2]     = make_float4(px, py, pz, 0.0f);
    bkt[(size_t)(b * CAP + slot) * 2 + 1] = make_float4(nrm[3*i+0], nrm[3*i+1], nrm[3*i+2], 0.0f);
  }
}

// ================= fwd_zr: fused raster (+W grid) + z-FFT + Hermitian unpack ==========
// Outputs (w in [0,64], layout [w][x][y]): V0, V1, V2*fz(w). W (raster of ones) -> Wg real.
__global__ __launch_bounds__(512, 6) void fwd_zr(const float4* __restrict__ bkt,
                                                 const int* __restrict__ counts,
                                                 float2* __restrict__ V0,
                                                 float2* __restrict__ V1,
                                                 float2* __restrict__ V2,
                                                 float* __restrict__ Wg) {
  __shared__ float2 sp[16][129];   // v0 + i*v1
  __shared__ float2 s2[16][129];   // v2
  __shared__ float2 S[16][128];    // FFT scratch; first 2048 floats reused as W accum
  __shared__ float2 tw[128];
  float* Wf = (float*)S;
  int tid = threadIdx.x;
  init_tw(tw, tid);
  int x = blockIdx.x >> 3, y0 = (blockIdx.x & 7) << 4;
  for (int e = tid; e < 16 * 129; e += 512) {
    (&sp[0][0])[e] = make_float2(0.0f, 0.0f);
    (&s2[0][0])[e] = make_float2(0.0f, 0.0f);
  }
  for (int e = tid; e < 2048; e += 512) Wf[e] = 0.0f;
  __syncthreads();
  for (int tt = tid; tt < 2 * 17 * CAP; tt += 512) {
    int side = tt / (17 * CAP);
    int jj = tt - side * (17 * CAP);
    int j = jj >> 5, slot = jj & 31;          // CAP == 32
    int by = (y0 - 1 + j) & 127;
    int bx = side ? ((x + 127) & 127) : x;
    int b = (bx << 7) + by;
    int cnt = counts[b]; if (cnt > CAP) cnt = CAP;
    if (slot < cnt) {
      float4 P  = bkt[(size_t)(b * CAP + slot) * 2];
      float4 Nm = bkt[(size_t)(b * CAP + slot) * 2 + 1];
      float tx = P.x*128.0f, ty = P.y*128.0f, tz = P.z*128.0f;
      float fx = tx - floorf(tx), fy = ty - floorf(ty), fz = tz - floorf(tz);
      int ly = ((int)floorf(ty)) & 127, lz = ((int)floorf(tz)) & 127;
      int z1 = (lz + 1) & 127;
      float wx = side ? fx : (1.0f - fx);
      #pragma unroll
      for (int yc = 0; yc < 2; yc++) {
        int yy = yc ? ((ly + 1) & 127) : ly;
        float wy = yc ? fy : (1.0f - fy);
        int l = (yy - y0) & 127;
        if (l < 16) {
          float w0 = wx*wy*(1.0f - fz), w1 = wx*wy*fz;
          atomicAdd(&sp[l][lz].x, w0*Nm.x); atomicAdd(&sp[l][lz].y, w0*Nm.y);
          atomicAdd(&sp[l][z1].x, w1*Nm.x); atomicAdd(&sp[l][z1].y, w1*Nm.y);
          atomicAdd(&s2[l][lz].x, w0*Nm.z);
          atomicAdd(&s2[l][z1].x, w1*Nm.z);
          atomicAdd(&Wf[l*128 + lz], w0);
          atomicAdd(&Wf[l*128 + z1], w1);
        }
      }
    }
  }
  __syncthreads();
  // write W grid (real space) before S is clobbered by FFT
  for (int e = tid; e < 2048; e += 512)
    Wg[(x * 128 + y0 + (e >> 7)) * 128 + (e & 127)] = Wf[e];
  __syncthreads();
  fft16<-1>(&sp[0][0], 129, S, tw, tid);
  // Hermitian unpack: v0hat=(A+conj(B))/2, v1hat=(A-conj(B))/(2i)
  for (int e = tid; e < 65 * 16; e += 512) {
    int w = e >> 4, l = e & 15;
    float2 A = sp[l][w];
    float2 B = sp[l][(128 - w) & 127];
    size_t o = (size_t)w * 16384 + x * 128 + y0 + l;
    V0[o] = make_float2(0.5f * (A.x + B.x), 0.5f * (A.y - B.y));
    V1[o] = make_float2(0.5f * (A.y + B.y), 0.5f * (B.x - A.x));
  }
  fft16<-1>(&s2[0][0], 129, S, tw, tid);
  for (int e = tid; e < 65 * 16; e += 512) {
    int w = e >> 4, l = e & 15;
    float fzw = (float)(w < 64 ? w : w - 128);   // bake fz into V2
    float2 v = s2[l][w];
    V2[(size_t)w * 16384 + x * 128 + y0 + l] = make_float2(fzw * v.x, fzw * v.y);
  }
}

// ================= fwd_y: y-FFT; y=0: V0 plain; y=1: V12 = fy*FFT(V1) + FFT(V2') ======
__global__ __launch_bounds__(512, 6) void fwd_y(float2* __restrict__ V0,
                                                float2* __restrict__ V1,
                                                float2* __restrict__ V2) {
  __shared__ float2 sc[16][129];
  __shared__ float2 sc2[16][129];
  __shared__ float2 S[16][128];
  __shared__ float2 tw[128];
  int tid = threadIdx.x;
  init_tw(tw, tid);
  if (blockIdx.y == 0) {
    float2* D = V0 + (size_t)blockIdx.x * 2048;
    for (int e = tid; e < 2048; e += 512) sc[e >> 7][e & 127] = D[e];
    __syncthreads();
    fft16<-1>(&sc[0][0], 129, S, tw, tid);
    for (int e = tid; e < 2048; e += 512) D[e] = sc[e >> 7][e & 127];
  } else {
    float2* D1 = V1 + (size_t)blockIdx.x * 2048;
    float2* D2 = V2 + (size_t)blockIdx.x * 2048;
    for (int e = tid; e < 2048; e += 512) {
      sc [e >> 7][e & 127] = D1[e];
      sc2[e >> 7][e & 127] = D2[e];
    }
    __syncthreads();
    fft16<-1>(&sc[0][0],  129, S, tw, tid);
    fft16<-1>(&sc2[0][0], 129, S, tw, tid);
    for (int e = tid; e < 2048; e += 512) {
      int ky = e & 127;
      float fy = (float)(ky < 64 ? ky : ky - 128);
      float2 a = sc[e >> 7][ky], b = sc2[e >> 7][ky];
      D1[e] = make_float2(fy * a.x + b.x, fy * a.y + b.y);  // V12 in place of V1
    }
  }
}

// ================= xspec: fwd x-FFT (2ch) + spectral + inv x-FFT, in place into V0 =====
__global__ __launch_bounds__(512, 6) void pass_xspec(float2* __restrict__ V0,
                                                     const float2* __restrict__ V12) {
  __shared__ float2 T0[16][129], T12[16][129];
  __shared__ float2 S[16][128];
  __shared__ float2 tw[128];
  int tid = threadIdx.x;
  init_tw(tw, tid);
  int w = blockIdx.x, T = blockIdx.y;
  int ky0 = T << 4;
  for (int e = tid; e < 2048; e += 512) {
    int xx = e >> 4, i = e & 15;
    size_t o = (size_t)w * 16384 + xx * 128 + ky0 + i;
    T0[i][xx]  = V0[o];
    T12[i][xx] = V12[o];
  }
  __syncthreads();
  fft16<-1>(&T0[0][0],  129, S, tw, tid);
  fft16<-1>(&T12[0][0], 129, S, tw, tid);
  float fz = (float)(w < 64 ? w : w - 128);
  for (int e = tid; e < 2048; e += 512) {
    int i = e >> 7, kx = e & 127;
    int ky = ky0 + i;
    float2 v0 = T0[i][kx], v12 = T12[i][kx];
    float fx = (float)(kx < 64 ? kx : kx - 128);
    float fy = (float)(ky < 64 ? ky : ky - 128);
    float u2 = fx * fx + fy * fy + fz * fz;
    float gg = __expf(-0.0030517578125f * u2);   // -2*(5/128)^2*u2
    float coef = gg / (6.28318530717958648f * (u2 + 1e-6f)) * (1.0f / 2097152.0f);
    float dre = fx * v0.x + v12.x;               // v12 = fy*v1hat + fz*v2hat
    float dim = fx * v0.y + v12.y;
    T0[i][kx] = make_float2(coef * dim, -coef * dre);  // (-i)*(a+bi) = (b,-a)
  }
  __syncthreads();
  fft16<1>(&T0[0][0], 129, S, tw, tid);
  for (int e = tid; e < 2048; e += 512) {
    int xx = e >> 4, i = e & 15;
    V0[(size_t)w * 16384 + xx * 128 + ky0 + i] = T0[i][xx];
  }
}

// ================= inv_y: inverse y-FFT on contiguous lines, in place (V0) =============
__global__ __launch_bounds__(512, 6) void inv_y(float2* __restrict__ V0) {
  __shared__ float2 sc[16][129];
  __shared__ float2 S[16][128];
  __shared__ float2 tw[128];
  int tid = threadIdx.x;
  init_tw(tw, tid);
  float2* D = V0 + (size_t)blockIdx.x * 2048;
  for (int e = tid; e < 2048; e += 512) sc[e >> 7][e & 127] = D[e];
  __syncthreads();
  fft16<1>(&sc[0][0], 129, S, tw, tid);
  for (int e = tid; e < 2048; e += 512) D[e] = sc[e >> 7][e & 127];
}

// ================= inv_z: Hermitian c2r inverse w-FFT + <W,chi> dot, write chi =========
__global__ __launch_bounds__(512, 6) void inv_z(const float2* __restrict__ V0,
                                                const float* __restrict__ Wg,
                                                float* __restrict__ chi,
                                                float* __restrict__ sum) {
  __shared__ float2 sc[16][129];
  __shared__ float2 S[16][128];
  __shared__ float2 tw[128];
  int tid = threadIdx.x;
  init_tw(tw, tid);
  int x = blockIdx.x >> 3, y0 = (blockIdx.x & 7) << 4;
  for (int e = tid; e < 65 * 16; e += 512) {
    int w = e >> 4, i = e & 15;
    sc[i][w] = V0[(size_t)w * 16384 + x * 128 + y0 + i];
  }
  __syncthreads();
  for (int e = tid; e < 63 * 16; e += 512) {
    int w = 65 + (e >> 4), i = e & 15;
    float2 c = sc[i][128 - w];
    sc[i][w] = make_float2(c.x, -c.y);
  }
  __syncthreads();
  fft16<1>(&sc[0][0], 129, S, tw, tid);
  float partial = 0.0f;
  for (int e = tid; e < 2048; e += 512) {
    int i = e >> 7, z = e & 127;
    float c = sc[i][z].x;
    int gi = (x * 128 + y0 + i) * 128 + z;
    chi[gi] = c;
    partial += c * Wg[gi];
  }
  #pragma unroll
  for (int off = 32; off > 0; off >>= 1) partial += __shfl_down(partial, off, 64);
  if ((tid & 63) == 0) atomicAdd(sum, partial);
}

// ================= finalize =================
__global__ __launch_bounds__(256) void finalize(const float* __restrict__ chi,
                                                const float* __restrict__ sum,
                                                float* __restrict__ out, int npts) {
  int i = blockIdx.x * 256 + threadIdx.x;
  float mean = sum[0] / (float)npts;
  float chi0 = chi[0] - mean;
  float scale = 0.5f / fabsf(chi0);
  out[i] = scale * (chi[i] - mean);
}

// ================= launch =================
extern "C" void kernel_launch(void* const* d_in, const int* in_sizes, int n_in,
                              void* d_out, int out_size, void* d_ws, size_t ws_size,
                              hipStream_t stream) {
  const float* pts = (const float*)d_in[0];
  const float* nrm = (const float*)d_in[1];
  float* out = (float*)d_out;
  int npts = in_sizes[0] / 3;  // 131072

  const size_t HSLICES = 65ull * 16384;  // half-spectrum elems per channel
  char* p = (char*)d_ws;
  float2* V0     = (float2*)p;  p += HSLICES * sizeof(float2);                 // 8.5 MB
  float2* V1     = (float2*)p;  p += HSLICES * sizeof(float2);                 // 8.5 MB
  float2* V2     = (float2*)p;  p += HSLICES * sizeof(float2);                 // 8.5 MB
  float4* bkt    = (float4*)p;  p += (size_t)16384 * CAP * 2 * sizeof(float4); // 16.8 MB
  float*  chi    = (float*)p;   p += (size_t)NCELLS * sizeof(float);           // 8.4 MB
  float*  Wg     = (float*)p;   p += (size_t)NCELLS * sizeof(float);           // 8.4 MB
  int*    counts = (int*)p;     p += 16384 * sizeof(int);
  float*  sum    = (float*)p;

  hipMemsetAsync(counts, 0, 16384 * sizeof(int) + sizeof(float), stream);  // counts + sum

  scatter_direct<<<(npts + 255) / 256, 256, 0, stream>>>(pts, nrm, counts, bkt, npts);
  fwd_zr<<<1024, 512, 0, stream>>>(bkt, counts, V0, V1, V2, Wg);
  fwd_y<<<dim3(520, 2), 512, 0, stream>>>(V0, V1, V2);
  pass_xspec<<<dim3(65, 8), 512, 0, stream>>>(V0, V1);
  inv_y<<<520, 512, 0, stream>>>(V0);
  inv_z<<<1024, 512, 0, stream>>>(V0, Wg, chi, sum);
  finalize<<<NCELLS / 256, 256, 0, stream>>>(chi, sum, out, npts);
}

// Round 11
// 166.108 us; speedup vs baseline: 2.5888x; 1.5490x over previous
//
#include <hip/hip_runtime.h>
#include <math.h>

#define NCELLS 2097152  // 128^3
#define CAP 32          // bucket capacity (mean occupancy 8; P(>32) ~ 1e-10)

// ================= complex helpers =================
__device__ __forceinline__ float2 cadd(float2 a, float2 b){ return make_float2(a.x+b.x, a.y+b.y); }
__device__ __forceinline__ float2 csub(float2 a, float2 b){ return make_float2(a.x-b.x, a.y-b.y); }
template<int DIR>
__device__ __forceinline__ float2 ctw(float2 b, float2 w) {
  if (DIR < 0) return make_float2(b.x*w.x - b.y*w.y, b.x*w.y + b.y*w.x);
  else         return make_float2(b.x*w.x + b.y*w.y, b.y*w.x - b.x*w.y);
}

// tw[Ns+k] = exp(-i*pi*k/Ns), indices 1..127
__device__ __forceinline__ void init_tw(float2* tw, int tid) {
  if (tid >= 1 && tid < 128) {
    int Ns = 1 << (31 - __clz(tid));
    int k = tid - Ns;
    float ang = -3.14159265358979323846f * (float)k / (float)Ns;
    float s, c;
    sincosf(ang, &s, &c);
    tw[tid] = make_float2(c, s);
  }
}

// ===== Stockham FFT, 16 lines of 128 in LDS, radix 4-4-8 (3 stages, last in-place).
// base rows stride ls (=129 padded). Scratch S[16][128]. 512 threads.
template<int DIR>
__device__ __forceinline__ void fft16(float2* __restrict__ base, int ls,
                                      float2 (*__restrict__ S)[128],
                                      const float2* __restrict__ tw, int tid) {
  const float SQ2 = 0.70710678118654752f;
  int l = tid >> 5, j = tid & 31;
  float2* B = base + l * ls;
  { // stage 0: radix-4, Ns=1, B -> S
    float2 a = B[j], b = B[j+32], c = B[j+64], d = B[j+96];
    float2 t0 = cadd(a,c), t1 = csub(a,c), t2 = cadd(b,d), t3s = csub(b,d);
    float2 t3 = (DIR<0) ? make_float2(t3s.y,-t3s.x) : make_float2(-t3s.y,t3s.x);
    int o = j << 2;
    S[l][o] = cadd(t0,t2); S[l][o+1] = cadd(t1,t3);
    S[l][o+2] = csub(t0,t2); S[l][o+3] = csub(t1,t3);
  }
  __syncthreads();
  { // stage 1: radix-4, Ns=4, S -> B
    int k = j & 3;
    float2 a = S[l][j], b = S[l][j+32], c = S[l][j+64], d = S[l][j+96];
    float2 w1 = tw[8+k], w2 = tw[4+k];
    float2 w3 = make_float2(w1.x*w2.x - w1.y*w2.y, w1.x*w2.y + w1.y*w2.x);
    b = ctw<DIR>(b,w1); c = ctw<DIR>(c,w2); d = ctw<DIR>(d,w3);
    float2 t0 = cadd(a,c), t1 = csub(a,c), t2 = cadd(b,d), t3s = csub(b,d);
    float2 t3 = (DIR<0) ? make_float2(t3s.y,-t3s.x) : make_float2(-t3s.y,t3s.x);
    int o = ((j>>2)<<4) + k;
    B[o] = cadd(t0,t2); B[o+4] = cadd(t1,t3);
    B[o+8] = csub(t0,t2); B[o+12] = csub(t1,t3);
  }
  __syncthreads();
  if (tid < 256) { // stage 2: radix-8, Ns=16, B -> B IN PLACE (task k owns {k+16m})
    int l2 = tid >> 4, k = tid & 15;
    float2* B2 = base + l2 * ls;
    float2 x0=B2[k],    x1=B2[k+16], x2=B2[k+32], x3=B2[k+48],
           x4=B2[k+64], x5=B2[k+80], x6=B2[k+96], x7=B2[k+112];
    float2 w1 = tw[64+k], w2 = tw[32+k], w4 = tw[16+k];
    float2 w3 = make_float2(w1.x*w2.x - w1.y*w2.y, w1.x*w2.y + w1.y*w2.x);
    float2 w5 = make_float2(w4.x*w1.x - w4.y*w1.y, w4.x*w1.y + w4.y*w1.x);
    float2 w6 = make_float2(w4.x*w2.x - w4.y*w2.y, w4.x*w2.y + w4.y*w2.x);
    float2 w7 = make_float2(w4.x*w3.x - w4.y*w3.y, w4.x*w3.y + w4.y*w3.x);
    x1 = ctw<DIR>(x1,w1); x2 = ctw<DIR>(x2,w2); x3 = ctw<DIR>(x3,w3);
    x4 = ctw<DIR>(x4,w4); x5 = ctw<DIR>(x5,w5); x6 = ctw<DIR>(x6,w6); x7 = ctw<DIR>(x7,w7);
    float2 e0=cadd(x0,x4), e1=cadd(x1,x5), e2=cadd(x2,x6), e3=cadd(x3,x7);
    float2 o0=csub(x0,x4), o1=csub(x1,x5), o2=csub(x2,x6), o3=csub(x3,x7);
    o1 = (DIR<0)? make_float2(SQ2*(o1.x+o1.y), SQ2*(o1.y-o1.x))
                : make_float2(SQ2*(o1.x-o1.y), SQ2*(o1.x+o1.y));
    o2 = (DIR<0)? make_float2(o2.y,-o2.x) : make_float2(-o2.y,o2.x);
    o3 = (DIR<0)? make_float2(SQ2*(o3.y-o3.x), -SQ2*(o3.x+o3.y))
                : make_float2(-SQ2*(o3.x+o3.y), SQ2*(o3.x-o3.y));
    { // DFT4(evens) -> X[2r] at k+32r
      float2 t0=cadd(e0,e2), t1=csub(e0,e2), t2=cadd(e1,e3), t3s=csub(e1,e3);
      float2 t3 = (DIR<0)? make_float2(t3s.y,-t3s.x) : make_float2(-t3s.y,t3s.x);
      B2[k]    = cadd(t0,t2); B2[k+32] = cadd(t1,t3);
      B2[k+64] = csub(t0,t2); B2[k+96] = csub(t1,t3);
    }
    { // DFT4(odds) -> X[2r+1] at k+16+32r
      float2 t0=cadd(o0,o2), t1=csub(o0,o2), t2=cadd(o1,o3), t3s=csub(o1,o3);
      float2 t3 = (DIR<0)? make_float2(t3s.y,-t3s.x) : make_float2(-t3s.y,t3s.x);
      B2[k+16] = cadd(t0,t2); B2[k+48] = cadd(t1,t3);
      B2[k+80] = csub(t0,t2); B2[k+112] = csub(t1,t3);
    }
  }
  __syncthreads();
}

// ================= direct bucket scatter (fixed capacity, no scan) =================
__global__ __launch_bounds__(256) void scatter_direct(const float* __restrict__ pts,
                                                      const float* __restrict__ nrm,
                                                      int* __restrict__ counts,
                                                      float4* __restrict__ bkt, int npts) {
  int i = blockIdx.x * 256 + threadIdx.x;
  if (i >= npts) return;
  float px = pts[3*i+0], py = pts[3*i+1], pz = pts[3*i+2];
  int lx = ((int)floorf(px * 128.0f)) & 127;
  int ly = ((int)floorf(py * 128.0f)) & 127;
  int b = (lx << 7) + ly;
  int slot = atomicAdd(counts + b, 1);
  if (slot < CAP) {
    bkt[(size_t)(b * CAP + slot) * 2]     = make_float4(px, py, pz, 0.0f);
    bkt[(size_t)(b * CAP + slot) * 2 + 1] = make_float4(nrm[3*i+0], nrm[3*i+1], nrm[3*i+2], 0.0f);
  }
}

// ================= fwd_zr: fused raster (+W grid) + z-FFT + Hermitian unpack ==========
// Outputs (w in [0,64], layout [w][x][y]): V0, V1, V2*fz(w). W (raster of ones) -> Wg real.
__global__ __launch_bounds__(512, 6) void fwd_zr(const float4* __restrict__ bkt,
                                                 const int* __restrict__ counts,
                                                 float2* __restrict__ V0,
                                                 float2* __restrict__ V1,
                                                 float2* __restrict__ V2,
                                                 float* __restrict__ Wg) {
  __shared__ float2 sp[16][129];   // v0 + i*v1
  __shared__ float2 s2[16][129];   // v2
  __shared__ float2 S[16][128];    // FFT scratch; first 2048 floats reused as W accum
  __shared__ float2 tw[128];
  float* Wf = (float*)S;
  int tid = threadIdx.x;
  init_tw(tw, tid);
  int x = blockIdx.x >> 3, y0 = (blockIdx.x & 7) << 4;
  for (int e = tid; e < 16 * 129; e += 512) {
    (&sp[0][0])[e] = make_float2(0.0f, 0.0f);
    (&s2[0][0])[e] = make_float2(0.0f, 0.0f);
  }
  for (int e = tid; e < 2048; e += 512) Wf[e] = 0.0f;
  __syncthreads();
  for (int tt = tid; tt < 2 * 17 * CAP; tt += 512) {
    int side = tt / (17 * CAP);
    int jj = tt - side * (17 * CAP);
    int j = jj >> 5, slot = jj & 31;          // CAP == 32
    int by = (y0 - 1 + j) & 127;
    int bx = side ? ((x + 127) & 127) : x;
    int b = (bx << 7) + by;
    int cnt = counts[b]; if (cnt > CAP) cnt = CAP;
    if (slot < cnt) {
      float4 P  = bkt[(size_t)(b * CAP + slot) * 2];
      float4 Nm = bkt[(size_t)(b * CAP + slot) * 2 + 1];
      float tx = P.x*128.0f, ty = P.y*128.0f, tz = P.z*128.0f;
      float fx = tx - floorf(tx), fy = ty - floorf(ty), fz = tz - floorf(tz);
      int ly = ((int)floorf(ty)) & 127, lz = ((int)floorf(tz)) & 127;
      int z1 = (lz + 1) & 127;
      float wx = side ? fx : (1.0f - fx);
      #pragma unroll
      for (int yc = 0; yc < 2; yc++) {
        int yy = yc ? ((ly + 1) & 127) : ly;
        float wy = yc ? fy : (1.0f - fy);
        int l = (yy - y0) & 127;
        if (l < 16) {
          float w0 = wx*wy*(1.0f - fz), w1 = wx*wy*fz;
          atomicAdd(&sp[l][lz].x, w0*Nm.x); atomicAdd(&sp[l][lz].y, w0*Nm.y);
          atomicAdd(&sp[l][z1].x, w1*Nm.x); atomicAdd(&sp[l][z1].y, w1*Nm.y);
          atomicAdd(&s2[l][lz].x, w0*Nm.z);
          atomicAdd(&s2[l][z1].x, w1*Nm.z);
          atomicAdd(&Wf[l*128 + lz], w0);
          atomicAdd(&Wf[l*128 + z1], w1);
        }
      }
    }
  }
  __syncthreads();
  // write W grid (real space) before S is clobbered by FFT
  for (int e = tid; e < 2048; e += 512)
    Wg[(x * 128 + y0 + (e >> 7)) * 128 + (e & 127)] = Wf[e];
  __syncthreads();
  fft16<-1>(&sp[0][0], 129, S, tw, tid);
  // Hermitian unpack: v0hat=(A+conj(B))/2, v1hat=(A-conj(B))/(2i)
  for (int e = tid; e < 65 * 16; e += 512) {
    int w = e >> 4, l = e & 15;
    float2 A = sp[l][w];
    float2 B = sp[l][(128 - w) & 127];
    size_t o = (size_t)w * 16384 + x * 128 + y0 + l;
    V0[o] = make_float2(0.5f * (A.x + B.x), 0.5f * (A.y - B.y));
    V1[o] = make_float2(0.5f * (A.y + B.y), 0.5f * (B.x - A.x));
  }
  fft16<-1>(&s2[0][0], 129, S, tw, tid);
  for (int e = tid; e < 65 * 16; e += 512) {
    int w = e >> 4, l = e & 15;
    float fzw = (float)(w < 64 ? w : w - 128);   // bake fz into V2
    float2 v = s2[l][w];
    V2[(size_t)w * 16384 + x * 128 + y0 + l] = make_float2(fzw * v.x, fzw * v.y);
  }
}

// ================= fwd_y: y-FFT; y=0: V0 plain; y=1: V12 = fy*FFT(V1) + FFT(V2') ======
__global__ __launch_bounds__(512, 6) void fwd_y(float2* __restrict__ V0,
                                                float2* __restrict__ V1,
                                                float2* __restrict__ V2) {
  __shared__ float2 sc[16][129];
  __shared__ float2 sc2[16][129];
  __shared__ float2 S[16][128];
  __shared__ float2 tw[128];
  int tid = threadIdx.x;
  init_tw(tw, tid);
  if (blockIdx.y == 0) {
    float2* D = V0 + (size_t)blockIdx.x * 2048;
    for (int e = tid; e < 2048; e += 512) sc[e >> 7][e & 127] = D[e];
    __syncthreads();
    fft16<-1>(&sc[0][0], 129, S, tw, tid);
    for (int e = tid; e < 2048; e += 512) D[e] = sc[e >> 7][e & 127];
  } else {
    float2* D1 = V1 + (size_t)blockIdx.x * 2048;
    float2* D2 = V2 + (size_t)blockIdx.x * 2048;
    for (int e = tid; e < 2048; e += 512) {
      sc [e >> 7][e & 127] = D1[e];
      sc2[e >> 7][e & 127] = D2[e];
    }
    __syncthreads();
    fft16<-1>(&sc[0][0],  129, S, tw, tid);
    fft16<-1>(&sc2[0][0], 129, S, tw, tid);
    for (int e = tid; e < 2048; e += 512) {
      int ky = e & 127;
      float fy = (float)(ky < 64 ? ky : ky - 128);
      float2 a = sc[e >> 7][ky], b = sc2[e >> 7][ky];
      D1[e] = make_float2(fy * a.x + b.x, fy * a.y + b.y);  // V12 in place of V1
    }
  }
}

// ================= xspec: fwd x-FFT (2ch) + spectral + inv x-FFT, in place into V0 =====
__global__ __launch_bounds__(512, 6) void pass_xspec(float2* __restrict__ V0,
                                                     const float2* __restrict__ V12) {
  __shared__ float2 T0[16][129], T12[16][129];
  __shared__ float2 S[16][128];
  __shared__ float2 tw[128];
  int tid = threadIdx.x;
  init_tw(tw, tid);
  int w = blockIdx.x, T = blockIdx.y;
  int ky0 = T << 4;
  for (int e = tid; e < 2048; e += 512) {
    int xx = e >> 4, i = e & 15;
    size_t o = (size_t)w * 16384 + xx * 128 + ky0 + i;
    T0[i][xx]  = V0[o];
    T12[i][xx] = V12[o];
  }
  __syncthreads();
  fft16<-1>(&T0[0][0],  129, S, tw, tid);
  fft16<-1>(&T12[0][0], 129, S, tw, tid);
  float fz = (float)(w < 64 ? w : w - 128);
  for (int e = tid; e < 2048; e += 512) {
    int i = e >> 7, kx = e & 127;
    int ky = ky0 + i;
    float2 v0 = T0[i][kx], v12 = T12[i][kx];
    float fx = (float)(kx < 64 ? kx : kx - 128);
    float fy = (float)(ky < 64 ? ky : ky - 128);
    float u2 = fx * fx + fy * fy + fz * fz;
    float gg = __expf(-0.0030517578125f * u2);   // -2*(5/128)^2*u2
    float coef = gg / (6.28318530717958648f * (u2 + 1e-6f)) * (1.0f / 2097152.0f);
    float dre = fx * v0.x + v12.x;               // v12 = fy*v1hat + fz*v2hat
    float dim = fx * v0.y + v12.y;
    T0[i][kx] = make_float2(coef * dim, -coef * dre);  // (-i)*(a+bi) = (b,-a)
  }
  __syncthreads();
  fft16<1>(&T0[0][0], 129, S, tw, tid);
  for (int e = tid; e < 2048; e += 512) {
    int xx = e >> 4, i = e & 15;
    V0[(size_t)w * 16384 + xx * 128 + ky0 + i] = T0[i][xx];
  }
}

// ================= inv_y: inverse y-FFT on contiguous lines, in place (V0) =============
__global__ __launch_bounds__(512, 6) void inv_y(float2* __restrict__ V0) {
  __shared__ float2 sc[16][129];
  __shared__ float2 S[16][128];
  __shared__ float2 tw[128];
  int tid = threadIdx.x;
  init_tw(tw, tid);
  float2* D = V0 + (size_t)blockIdx.x * 2048;
  for (int e = tid; e < 2048; e += 512) sc[e >> 7][e & 127] = D[e];
  __syncthreads();
  fft16<1>(&sc[0][0], 129, S, tw, tid);
  for (int e = tid; e < 2048; e += 512) D[e] = sc[e >> 7][e & 127];
}

// ================= inv_z: Hermitian c2r inverse w-FFT + <W,chi> dot, write chi =========
// ONE global atomic per block (per-block LDS reduction) — 8192 same-address atomics
// serialized at ~13ns each was the round-10 110us stall.
__global__ __launch_bounds__(512, 6) void inv_z(const float2* __restrict__ V0,
                                                const float* __restrict__ Wg,
                                                float* __restrict__ chi,
                                                float* __restrict__ sum) {
  __shared__ float2 sc[16][129];
  __shared__ float2 S[16][128];
  __shared__ float2 tw[128];
  __shared__ float wsum[8];
  int tid = threadIdx.x;
  init_tw(tw, tid);
  int x = blockIdx.x >> 3, y0 = (blockIdx.x & 7) << 4;
  for (int e = tid; e < 65 * 16; e += 512) {
    int w = e >> 4, i = e & 15;
    sc[i][w] = V0[(size_t)w * 16384 + x * 128 + y0 + i];
  }
  __syncthreads();
  for (int e = tid; e < 63 * 16; e += 512) {
    int w = 65 + (e >> 4), i = e & 15;
    float2 c = sc[i][128 - w];
    sc[i][w] = make_float2(c.x, -c.y);
  }
  __syncthreads();
  fft16<1>(&sc[0][0], 129, S, tw, tid);
  float partial = 0.0f;
  for (int e = tid; e < 2048; e += 512) {
    int i = e >> 7, z = e & 127;
    float c = sc[i][z].x;
    int gi = (x * 128 + y0 + i) * 128 + z;
    chi[gi] = c;
    partial += c * Wg[gi];
  }
  #pragma unroll
  for (int off = 32; off > 0; off >>= 1) partial += __shfl_down(partial, off, 64);
  if ((tid & 63) == 0) wsum[tid >> 6] = partial;
  __syncthreads();
  if (tid == 0) {
    float s = 0.0f;
    #pragma unroll
    for (int q = 0; q < 8; q++) s += wsum[q];
    atomicAdd(sum, s);
  }
}

// ================= finalize =================
__global__ __launch_bounds__(256) void finalize(const float* __restrict__ chi,
                                                const float* __restrict__ sum,
                                                float* __restrict__ out, int npts) {
  int i = blockIdx.x * 256 + threadIdx.x;
  float mean = sum[0] / (float)npts;
  float chi0 = chi[0] - mean;
  float scale = 0.5f / fabsf(chi0);
  out[i] = scale * (chi[i] - mean);
}

// ================= launch =================
extern "C" void kernel_launch(void* const* d_in, const int* in_sizes, int n_in,
                              void* d_out, int out_size, void* d_ws, size_t ws_size,
                              hipStream_t stream) {
  const float* pts = (const float*)d_in[0];
  const float* nrm = (const float*)d_in[1];
  float* out = (float*)d_out;
  int npts = in_sizes[0] / 3;  // 131072

  const size_t HSLICES = 65ull * 16384;  // half-spectrum elems per channel
  char* p = (char*)d_ws;
  float2* V0     = (float2*)p;  p += HSLICES * sizeof(float2);                 // 8.5 MB
  float2* V1     = (float2*)p;  p += HSLICES * sizeof(float2);                 // 8.5 MB
  float2* V2     = (float2*)p;  p += HSLICES * sizeof(float2);                 // 8.5 MB
  float4* bkt    = (float4*)p;  p += (size_t)16384 * CAP * 2 * sizeof(float4); // 16.8 MB
  float*  chi    = (float*)p;   p += (size_t)NCELLS * sizeof(float);           // 8.4 MB
  float*  Wg     = (float*)p;   p += (size_t)NCELLS * sizeof(float);           // 8.4 MB
  int*    counts = (int*)p;     p += 16384 * sizeof(int);
  float*  sum    = (float*)p;

  hipMemsetAsync(counts, 0, 16384 * sizeof(int) + sizeof(float), stream);  // counts + sum

  scatter_direct<<<(npts + 255) / 256, 256, 0, stream>>>(pts, nrm, counts, bkt, npts);
  fwd_zr<<<1024, 512, 0, stream>>>(bkt, counts, V0, V1, V2, Wg);
  fwd_y<<<dim3(520, 2), 512, 0, stream>>>(V0, V1, V2);
  pass_xspec<<<dim3(65, 8), 512, 0, stream>>>(V0, V1);
  inv_y<<<520, 512, 0, stream>>>(V0);
  inv_z<<<1024, 512, 0, stream>>>(V0, Wg, chi, sum);
  finalize<<<NCELLS / 256, 256, 0, stream>>>(chi, sum, out, npts);
}

// Round 12
// 152.202 us; speedup vs baseline: 2.8253x; 1.0914x over previous
//
#include <hip/hip_runtime.h>
#include <math.h>

#define NCELLS 2097152  // 128^3
#define CAP 32          // bucket capacity (mean occupancy 8; P(>32) ~ 1e-10)

// ================= complex helpers =================
__device__ __forceinline__ float2 cadd(float2 a, float2 b){ return make_float2(a.x+b.x, a.y+b.y); }
__device__ __forceinline__ float2 csub(float2 a, float2 b){ return make_float2(a.x-b.x, a.y-b.y); }
template<int DIR>
__device__ __forceinline__ float2 ctw(float2 b, float2 w) {
  if (DIR < 0) return make_float2(b.x*w.x - b.y*w.y, b.x*w.y + b.y*w.x);
  else         return make_float2(b.x*w.x + b.y*w.y, b.y*w.x - b.x*w.y);
}

// tw[Ns+k] = exp(-i*pi*k/Ns), indices 1..127
__device__ __forceinline__ void init_tw(float2* tw, int tid) {
  if (tid >= 1 && tid < 128) {
    int Ns = 1 << (31 - __clz(tid));
    int k = tid - Ns;
    float ang = -3.14159265358979323846f * (float)k / (float)Ns;
    float s, c;
    sincosf(ang, &s, &c);
    tw[tid] = make_float2(c, s);
  }
}

// ===== Stockham FFT, 16 lines of 128 in LDS, radix 4-4-8 (3 stages, last in-place).
template<int DIR>
__device__ __forceinline__ void fft16(float2* __restrict__ base, int ls,
                                      float2 (*__restrict__ S)[128],
                                      const float2* __restrict__ tw, int tid) {
  const float SQ2 = 0.70710678118654752f;
  int l = tid >> 5, j = tid & 31;
  float2* B = base + l * ls;
  { // stage 0: radix-4, Ns=1, B -> S
    float2 a = B[j], b = B[j+32], c = B[j+64], d = B[j+96];
    float2 t0 = cadd(a,c), t1 = csub(a,c), t2 = cadd(b,d), t3s = csub(b,d);
    float2 t3 = (DIR<0) ? make_float2(t3s.y,-t3s.x) : make_float2(-t3s.y,t3s.x);
    int o = j << 2;
    S[l][o] = cadd(t0,t2); S[l][o+1] = cadd(t1,t3);
    S[l][o+2] = csub(t0,t2); S[l][o+3] = csub(t1,t3);
  }
  __syncthreads();
  { // stage 1: radix-4, Ns=4, S -> B
    int k = j & 3;
    float2 a = S[l][j], b = S[l][j+32], c = S[l][j+64], d = S[l][j+96];
    float2 w1 = tw[8+k], w2 = tw[4+k];
    float2 w3 = make_float2(w1.x*w2.x - w1.y*w2.y, w1.x*w2.y + w1.y*w2.x);
    b = ctw<DIR>(b,w1); c = ctw<DIR>(c,w2); d = ctw<DIR>(d,w3);
    float2 t0 = cadd(a,c), t1 = csub(a,c), t2 = cadd(b,d), t3s = csub(b,d);
    float2 t3 = (DIR<0) ? make_float2(t3s.y,-t3s.x) : make_float2(-t3s.y,t3s.x);
    int o = ((j>>2)<<4) + k;
    B[o] = cadd(t0,t2); B[o+4] = cadd(t1,t3);
    B[o+8] = csub(t0,t2); B[o+12] = csub(t1,t3);
  }
  __syncthreads();
  if (tid < 256) { // stage 2: radix-8, Ns=16, B -> B IN PLACE (task k owns {k+16m})
    int l2 = tid >> 4, k = tid & 15;
    float2* B2 = base + l2 * ls;
    float2 x0=B2[k],    x1=B2[k+16], x2=B2[k+32], x3=B2[k+48],
           x4=B2[k+64], x5=B2[k+80], x6=B2[k+96], x7=B2[k+112];
    float2 w1 = tw[64+k], w2 = tw[32+k], w4 = tw[16+k];
    float2 w3 = make_float2(w1.x*w2.x - w1.y*w2.y, w1.x*w2.y + w1.y*w2.x);
    float2 w5 = make_float2(w4.x*w1.x - w4.y*w1.y, w4.x*w1.y + w4.y*w1.x);
    float2 w6 = make_float2(w4.x*w2.x - w4.y*w2.y, w4.x*w2.y + w4.y*w2.x);
    float2 w7 = make_float2(w4.x*w3.x - w4.y*w3.y, w4.x*w3.y + w4.y*w3.x);
    x1 = ctw<DIR>(x1,w1); x2 = ctw<DIR>(x2,w2); x3 = ctw<DIR>(x3,w3);
    x4 = ctw<DIR>(x4,w4); x5 = ctw<DIR>(x5,w5); x6 = ctw<DIR>(x6,w6); x7 = ctw<DIR>(x7,w7);
    float2 e0=cadd(x0,x4), e1=cadd(x1,x5), e2=cadd(x2,x6), e3=cadd(x3,x7);
    float2 o0=csub(x0,x4), o1=csub(x1,x5), o2=csub(x2,x6), o3=csub(x3,x7);
    o1 = (DIR<0)? make_float2(SQ2*(o1.x+o1.y), SQ2*(o1.y-o1.x))
                : make_float2(SQ2*(o1.x-o1.y), SQ2*(o1.x+o1.y));
    o2 = (DIR<0)? make_float2(o2.y,-o2.x) : make_float2(-o2.y,o2.x);
    o3 = (DIR<0)? make_float2(SQ2*(o3.y-o3.x), -SQ2*(o3.x+o3.y))
                : make_float2(-SQ2*(o3.x+o3.y), SQ2*(o3.x-o3.y));
    {
      float2 t0=cadd(e0,e2), t1=csub(e0,e2), t2=cadd(e1,e3), t3s=csub(e1,e3);
      float2 t3 = (DIR<0)? make_float2(t3s.y,-t3s.x) : make_float2(-t3s.y,t3s.x);
      B2[k]    = cadd(t0,t2); B2[k+32] = cadd(t1,t3);
      B2[k+64] = csub(t0,t2); B2[k+96] = csub(t1,t3);
    }
    {
      float2 t0=cadd(o0,o2), t1=csub(o0,o2), t2=cadd(o1,o3), t3s=csub(o1,o3);
      float2 t3 = (DIR<0)? make_float2(t3s.y,-t3s.x) : make_float2(-t3s.y,t3s.x);
      B2[k+16] = cadd(t0,t2); B2[k+48] = cadd(t1,t3);
      B2[k+80] = csub(t0,t2); B2[k+112] = csub(t1,t3);
    }
  }
  __syncthreads();
}

// ================= direct bucket scatter (fixed capacity, no scan) =================
__global__ __launch_bounds__(256) void scatter_direct(const float* __restrict__ pts,
                                                      const float* __restrict__ nrm,
                                                      int* __restrict__ counts,
                                                      float4* __restrict__ bkt,
                                                      float* __restrict__ sum,
                                                      float* __restrict__ chi0acc, int npts) {
  int i = blockIdx.x * 256 + threadIdx.x;
  if (i >= npts) return;
  if (i == 0) { sum[0] = 0.0f; chi0acc[0] = 0.0f; }  // ordered before inv_y via dispatch chain
  float px = pts[3*i+0], py = pts[3*i+1], pz = pts[3*i+2];
  int lx = ((int)floorf(px * 128.0f)) & 127;
  int ly = ((int)floorf(py * 128.0f)) & 127;
  int b = (lx << 7) + ly;
  int slot = atomicAdd(counts + b, 1);
  if (slot < CAP) {
    bkt[(size_t)(b * CAP + slot) * 2]     = make_float4(px, py, pz, 0.0f);
    bkt[(size_t)(b * CAP + slot) * 2 + 1] = make_float4(nrm[3*i+0], nrm[3*i+1], nrm[3*i+2], 0.0f);
  }
}

// ================= fwd_zr: fused raster + z-FFT + Hermitian unpack ==================
// sp = v0 + i*v1 ; s2 = v2 + i*W (W = raster of ones). Outputs (w in [0,64], [w][x][y]):
// V0 = v0hat, V1 = v1hat, V2 = fz*v2hat, WZ = What_z.
__global__ __launch_bounds__(512, 6) void fwd_zr(const float4* __restrict__ bkt,
                                                 const int* __restrict__ counts,
                                                 float2* __restrict__ V0,
                                                 float2* __restrict__ V1,
                                                 float2* __restrict__ V2,
                                                 float2* __restrict__ WZ) {
  __shared__ float2 sp[16][129];
  __shared__ float2 s2[16][129];
  __shared__ float2 S[16][128];
  __shared__ float2 tw[128];
  int tid = threadIdx.x;
  init_tw(tw, tid);
  int x = blockIdx.x >> 3, y0 = (blockIdx.x & 7) << 4;
  for (int e = tid; e < 16 * 129; e += 512) {
    (&sp[0][0])[e] = make_float2(0.0f, 0.0f);
    (&s2[0][0])[e] = make_float2(0.0f, 0.0f);
  }
  __syncthreads();
  for (int tt = tid; tt < 2 * 17 * CAP; tt += 512) {
    int side = tt / (17 * CAP);
    int jj = tt - side * (17 * CAP);
    int j = jj >> 5, slot = jj & 31;          // CAP == 32
    int by = (y0 - 1 + j) & 127;
    int bx = side ? ((x + 127) & 127) : x;
    int b = (bx << 7) + by;
    int cnt = counts[b]; if (cnt > CAP) cnt = CAP;
    if (slot < cnt) {
      float4 P  = bkt[(size_t)(b * CAP + slot) * 2];
      float4 Nm = bkt[(size_t)(b * CAP + slot) * 2 + 1];
      float tx = P.x*128.0f, ty = P.y*128.0f, tz = P.z*128.0f;
      float fx = tx - floorf(tx), fy = ty - floorf(ty), fz = tz - floorf(tz);
      int ly = ((int)floorf(ty)) & 127, lz = ((int)floorf(tz)) & 127;
      int z1 = (lz + 1) & 127;
      float wx = side ? fx : (1.0f - fx);
      #pragma unroll
      for (int yc = 0; yc < 2; yc++) {
        int yy = yc ? ((ly + 1) & 127) : ly;
        float wy = yc ? fy : (1.0f - fy);
        int l = (yy - y0) & 127;
        if (l < 16) {
          float w0 = wx*wy*(1.0f - fz), w1 = wx*wy*fz;
          atomicAdd(&sp[l][lz].x, w0*Nm.x); atomicAdd(&sp[l][lz].y, w0*Nm.y);
          atomicAdd(&sp[l][z1].x, w1*Nm.x); atomicAdd(&sp[l][z1].y, w1*Nm.y);
          atomicAdd(&s2[l][lz].x, w0*Nm.z); atomicAdd(&s2[l][lz].y, w0);
          atomicAdd(&s2[l][z1].x, w1*Nm.z); atomicAdd(&s2[l][z1].y, w1);
        }
      }
    }
  }
  __syncthreads();
  fft16<-1>(&sp[0][0], 129, S, tw, tid);
  for (int e = tid; e < 65 * 16; e += 512) {
    int w = e >> 4, l = e & 15;
    float2 A = sp[l][w];
    float2 B = sp[l][(128 - w) & 127];
    size_t o = (size_t)w * 16384 + x * 128 + y0 + l;
    V0[o] = make_float2(0.5f * (A.x + B.x), 0.5f * (A.y - B.y));
    V1[o] = make_float2(0.5f * (A.y + B.y), 0.5f * (B.x - A.x));
  }
  fft16<-1>(&s2[0][0], 129, S, tw, tid);
  for (int e = tid; e < 65 * 16; e += 512) {
    int w = e >> 4, l = e & 15;
    float2 A = s2[l][w];
    float2 B = s2[l][(128 - w) & 127];
    float fzw = (float)(w < 64 ? w : w - 128);
    size_t o = (size_t)w * 16384 + x * 128 + y0 + l;
    V2[o] = make_float2(fzw * 0.5f * (A.x + B.x), fzw * 0.5f * (A.y - B.y));
    WZ[o] = make_float2(0.5f * (A.y + B.y), 0.5f * (B.x - A.x));
  }
}

// ================= fwd_y: y-FFT; y=0: V0 plain; y=1: V12 = fy*FFT(V1) + FFT(V2') ======
__global__ __launch_bounds__(512, 6) void fwd_y(float2* __restrict__ V0,
                                                float2* __restrict__ V1,
                                                float2* __restrict__ V2) {
  __shared__ float2 sc[16][129];
  __shared__ float2 sc2[16][129];
  __shared__ float2 S[16][128];
  __shared__ float2 tw[128];
  int tid = threadIdx.x;
  init_tw(tw, tid);
  if (blockIdx.y == 0) {
    float2* D = V0 + (size_t)blockIdx.x * 2048;
    for (int e = tid; e < 2048; e += 512) sc[e >> 7][e & 127] = D[e];
    __syncthreads();
    fft16<-1>(&sc[0][0], 129, S, tw, tid);
    for (int e = tid; e < 2048; e += 512) D[e] = sc[e >> 7][e & 127];
  } else {
    float2* D1 = V1 + (size_t)blockIdx.x * 2048;
    float2* D2 = V2 + (size_t)blockIdx.x * 2048;
    for (int e = tid; e < 2048; e += 512) {
      sc [e >> 7][e & 127] = D1[e];
      sc2[e >> 7][e & 127] = D2[e];
    }
    __syncthreads();
    fft16<-1>(&sc[0][0],  129, S, tw, tid);
    fft16<-1>(&sc2[0][0], 129, S, tw, tid);
    for (int e = tid; e < 2048; e += 512) {
      int ky = e & 127;
      float fy = (float)(ky < 64 ? ky : ky - 128);
      float2 a = sc[e >> 7][ky], b = sc2[e >> 7][ky];
      D1[e] = make_float2(fy * a.x + b.x, fy * a.y + b.y);  // V12 in place of V1
    }
  }
}

// ================= xspec: fwd x-FFT (2ch) + spectral + inv x-FFT, in place into V0 =====
__global__ __launch_bounds__(512, 6) void pass_xspec(float2* __restrict__ V0,
                                                     const float2* __restrict__ V12) {
  __shared__ float2 T0[16][129], T12[16][129];
  __shared__ float2 S[16][128];
  __shared__ float2 tw[128];
  int tid = threadIdx.x;
  init_tw(tw, tid);
  int w = blockIdx.x, T = blockIdx.y;
  int ky0 = T << 4;
  for (int e = tid; e < 2048; e += 512) {
    int xx = e >> 4, i = e & 15;
    size_t o = (size_t)w * 16384 + xx * 128 + ky0 + i;
    T0[i][xx]  = V0[o];
    T12[i][xx] = V12[o];
  }
  __syncthreads();
  fft16<-1>(&T0[0][0],  129, S, tw, tid);
  fft16<-1>(&T12[0][0], 129, S, tw, tid);
  float fz = (float)(w < 64 ? w : w - 128);
  for (int e = tid; e < 2048; e += 512) {
    int i = e >> 7, kx = e & 127;
    int ky = ky0 + i;
    float2 v0 = T0[i][kx], v12 = T12[i][kx];
    float fx = (float)(kx < 64 ? kx : kx - 128);
    float fy = (float)(ky < 64 ? ky : ky - 128);
    float u2 = fx * fx + fy * fy + fz * fz;
    float gg = __expf(-0.0030517578125f * u2);   // -2*(5/128)^2*u2
    float coef = gg / (6.28318530717958648f * (u2 + 1e-6f)) * (1.0f / 2097152.0f);
    float dre = fx * v0.x + v12.x;               // v12 = fy*v1hat + fz*v2hat
    float dim = fx * v0.y + v12.y;
    T0[i][kx] = make_float2(coef * dim, -coef * dre);  // (-i)*(a+bi) = (b,-a)
  }
  __syncthreads();
  fft16<1>(&T0[0][0], 129, S, tw, tid);
  for (int e = tid; e < 2048; e += 512) {
    int xx = e >> 4, i = e & 15;
    V0[(size_t)w * 16384 + xx * 128 + ky0 + i] = T0[i][xx];
  }
}

// ================= inv_y: inverse y-FFT + fused Parseval-z dot with WZ ================
// After FFT, sc holds Chat_z(w, x, y). Per column: sum_z W*chi = sum_w_herm Re(WZ*conj(C))
// with weight 2 for w in [1,63], 1 for w in {0,64}. One atomic per block.
__global__ __launch_bounds__(512, 6) void inv_y(float2* __restrict__ V0,
                                                const float2* __restrict__ WZ,
                                                float* __restrict__ sum,
                                                float* __restrict__ chi0acc) {
  __shared__ float2 sc[16][129];
  __shared__ float2 S[16][128];
  __shared__ float2 tw[128];
  __shared__ float wsum[8];
  int tid = threadIdx.x;
  init_tw(tw, tid);
  int t = blockIdx.x;
  int w = t >> 3, x0 = (t & 7) << 4;
  float2* D = V0 + (size_t)t * 2048;
  for (int e = tid; e < 2048; e += 512) sc[e >> 7][e & 127] = D[e];
  __syncthreads();
  fft16<1>(&sc[0][0], 129, S, tw, tid);
  float wgt = (w == 0 || w == 64) ? 1.0f : 2.0f;
  float partial = 0.0f;
  for (int e = tid; e < 2048; e += 512) {
    int l = e >> 7, y = e & 127;
    float2 cz = sc[l][y];
    float2 wz = WZ[(size_t)w * 16384 + (x0 + l) * 128 + y];
    partial += cz.x * wz.x + cz.y * wz.y;   // Re(WZ * conj(C))
    D[e] = cz;
  }
  partial *= wgt;
  #pragma unroll
  for (int off = 32; off > 0; off >>= 1) partial += __shfl_down(partial, off, 64);
  if ((tid & 63) == 0) wsum[tid >> 6] = partial;
  __syncthreads();
  if (tid == 0) {
    float s = 0.0f;
    #pragma unroll
    for (int q = 0; q < 8; q++) s += wsum[q];
    atomicAdd(sum, s);
    if (x0 == 0) atomicAdd(chi0acc, wgt * sc[0][0].x);  // chi(0,0,0) contribution
  }
}

// ================= inv_z: Hermitian c2r inverse w-FFT, write FINAL out directly ========
__global__ __launch_bounds__(512, 6) void inv_z(const float2* __restrict__ V0,
                                                const float* __restrict__ sum,
                                                const float* __restrict__ chi0acc,
                                                float* __restrict__ out, int npts) {
  __shared__ float2 sc[16][129];
  __shared__ float2 S[16][128];
  __shared__ float2 tw[128];
  int tid = threadIdx.x;
  init_tw(tw, tid);
  int x = blockIdx.x >> 3, y0 = (blockIdx.x & 7) << 4;
  for (int e = tid; e < 65 * 16; e += 512) {
    int w = e >> 4, i = e & 15;
    sc[i][w] = V0[(size_t)w * 16384 + x * 128 + y0 + i];
  }
  __syncthreads();
  for (int e = tid; e < 63 * 16; e += 512) {
    int w = 65 + (e >> 4), i = e & 15;
    float2 c = sc[i][128 - w];
    sc[i][w] = make_float2(c.x, -c.y);
  }
  __syncthreads();
  fft16<1>(&sc[0][0], 129, S, tw, tid);
  float mean = sum[0] / (float)npts;
  float scale = 0.5f / fabsf(chi0acc[0] - mean);
  for (int e = tid; e < 2048; e += 512) {
    int i = e >> 7, z = e & 127;
    out[(x * 128 + y0 + i) * 128 + z] = scale * (sc[i][z].x - mean);
  }
}

// ================= launch =================
extern "C" void kernel_launch(void* const* d_in, const int* in_sizes, int n_in,
                              void* d_out, int out_size, void* d_ws, size_t ws_size,
                              hipStream_t stream) {
  const float* pts = (const float*)d_in[0];
  const float* nrm = (const float*)d_in[1];
  float* out = (float*)d_out;
  int npts = in_sizes[0] / 3;  // 131072

  const size_t HSLICES = 65ull * 16384;  // half-spectrum elems per channel
  char* p = (char*)d_ws;
  float2* V0     = (float2*)p;  p += HSLICES * sizeof(float2);                 // 8.5 MB
  float2* V1     = (float2*)p;  p += HSLICES * sizeof(float2);                 // 8.5 MB
  float2* V2     = (float2*)p;  p += HSLICES * sizeof(float2);                 // 8.5 MB
  float2* WZ     = (float2*)p;  p += HSLICES * sizeof(float2);                 // 8.5 MB
  float4* bkt    = (float4*)p;  p += (size_t)16384 * CAP * 2 * sizeof(float4); // 16.8 MB
  int*    counts = (int*)p;     p += 16384 * sizeof(int);
  float*  sum    = (float*)p;   p += sizeof(float);
  float*  chi0acc= (float*)p;

  hipMemsetAsync(counts, 0, 16384 * sizeof(int), stream);

  scatter_direct<<<(npts + 255) / 256, 256, 0, stream>>>(pts, nrm, counts, bkt, sum, chi0acc, npts);
  fwd_zr<<<1024, 512, 0, stream>>>(bkt, counts, V0, V1, V2, WZ);
  fwd_y<<<dim3(520, 2), 512, 0, stream>>>(V0, V1, V2);
  pass_xspec<<<dim3(65, 8), 512, 0, stream>>>(V0, V1);
  inv_y<<<520, 512, 0, stream>>>(V0, WZ, sum, chi0acc);
  inv_z<<<1024, 512, 0, stream>>>(V0, sum, chi0acc, out, npts);
}